// Round 13
// baseline (42.214 us; speedup 1.0000x reference)
//
#include <hip/hip_runtime.h>

// Direct-Form-II biquad over [B=64][T=262144]; fully independent blocks via
// warm-up truncation (no inter-block sync).  v[t+1]=A v[t]+c x[t],
// A=[[-a1,1],[-a2,0]], c=[b1-a1*b0, b2-a2*b0], out[t]=b0 x[t]+v0[t].
// HIGH-RESIDENCY variant of the round-11 winner: LPT=16 -> LDS 17.4 KB/block
// -> 8 blocks/CU (needs VGPR<=64, hence xv[16] + shared scan matrix).
// Block g (batch b=g>>6, pos k=g&63) owns tile = 4096 samples; tile-start
// state from the 4096 preceding samples, zero-init (stable filter).
// Warm-up chunk = main chunk = 16 samples -> ONE matrix track for both scans.

constexpr int BATCH = 64;
constexpr int T_LEN = 262144;
constexpr int TPB   = 256;            // threads per block
constexpr int LPT   = 16;             // samples per thread
constexpr int TILE  = TPB * LPT;      // 4096 samples per block
constexpr int NBPB  = T_LEN / TILE;   // 64 blocks per batch chain
constexpr int NB    = BATCH * NBPB;   // 4096 blocks
constexpr int WUP   = 4096;           // warm-up samples (= one tile)

typedef float vfloat4 __attribute__((ext_vector_type(4)));

#define MATSQ(m00, m01, m10, m11)                                  \
    {                                                              \
        float n00 = fmaf(m00, m00, m01 * m10);                     \
        float n01 = fmaf(m00, m01, m01 * m11);                     \
        float n10 = fmaf(m10, m00, m11 * m10);                     \
        float n11 = fmaf(m10, m01, m11 * m11);                     \
        m00 = n00; m01 = n01; m10 = n10; m11 = n11;                \
    }

// composed 4-step update: v <- A^4 v + k3*xa + k2*xb + k1*xc + c*xd
#define CSTEP(p0, p1, xa, xb, xc, xd)                                        \
    {                                                                        \
        float n0 = fmaf(q00, p0, fmaf(q01, p1,                               \
                   fmaf(k3_0, (xa), fmaf(k2_0, (xb),                         \
                   fmaf(k1_0, (xc), c0 * (xd))))));                          \
        float n1 = fmaf(q10, p0, fmaf(q11, p1,                               \
                   fmaf(k3_1, (xa), fmaf(k2_1, (xb),                         \
                   fmaf(k1_1, (xc), c1 * (xd))))));                          \
        p0 = n0; p1 = n1;                                                    \
    }

__global__ __launch_bounds__(TPB, 8) void biquad_hires(
    const float* __restrict__ x, float* __restrict__ out,
    const float* __restrict__ pb0, const float* __restrict__ pb1,
    const float* __restrict__ pb2, const float* __restrict__ pa1,
    const float* __restrict__ pa2)
{
    __shared__ float lds[TPB][LPT + 1];   // 17,408 B
    __shared__ float swv[16];             // per wave w: [4w..4w+1]=W, [4w+2..3]=B

    const int tid  = threadIdx.x;
    const int lane = tid & 63;
    const int w    = tid >> 6;
    const int g    = blockIdx.x;
    const int b    = g >> 6;
    const int k    = g & (NBPB - 1);

    const float b0 = *pb0, b1 = *pb1, b2 = *pb2;
    const float a1 = *pa1, a2 = *pa2;
    const float na1 = -a1, na2 = -a2;

    // composed constants: c, k1=Ac, k2=A^2c, k3=A^3c, q=A^4
    const float c0 = fmaf(na1, b0, b1), c1 = fmaf(na2, b0, b2);
    const float A00 = na1, A01 = 1.f, A10 = na2, A11 = 0.f;
    const float k1_0 = fmaf(A00, c0, A01 * c1);
    const float k1_1 = fmaf(A10, c0, A11 * c1);
    float B00 = A00, B01 = A01, B10 = A10, B11 = A11;
    MATSQ(B00, B01, B10, B11);                           // A^2
    const float k2_0 = fmaf(B00, c0, B01 * c1);
    const float k2_1 = fmaf(B10, c0, B11 * c1);
    const float k3_0 = fmaf(B00, k1_0, B01 * k1_1);
    const float k3_1 = fmaf(B10, k1_0, B11 * k1_1);
    float q00 = B00, q01 = B01, q10 = B10, q11 = B11;
    MATSQ(q00, q01, q10, q11);                           // A^4

    const size_t base = (size_t)b * T_LEN + (size_t)k * TILE;

    // ---- warm-up: 4 x float4 per thread (64 B/lane stride), streamed ----
    float4 wq0, wq1, wq2, wq3;
    if (k > 0) {
        const float4* wsrc =
            reinterpret_cast<const float4*>(x + base - WUP) + tid * 4;
        wq0 = wsrc[0]; wq1 = wsrc[1]; wq2 = wsrc[2]; wq3 = wsrc[3];
    }

    // ---- stage tile: 4 coalesced float4 loads -> LDS (transposed) ----
    const float4* src = reinterpret_cast<const float4*>(x + base);
#pragma unroll
    for (int it = 0; it < TILE / (TPB * 4); ++it) {
        int idx = it * TPB + tid;
        float4 v = src[idx];
        int e = idx * 4, c = e >> 4, t = e & 15;
        lds[c][t] = v.x; lds[c][t + 1] = v.y;
        lds[c][t + 2] = v.z; lds[c][t + 3] = v.w;
    }

    // ---- warm-up pass 1: per-thread A^16 particular state ----
    float pW0 = 0.f, pW1 = 0.f;
    if (k > 0) {
        CSTEP(pW0, pW1, wq0.x, wq0.y, wq0.z, wq0.w);
        CSTEP(pW0, pW1, wq1.x, wq1.y, wq1.z, wq1.w);
        CSTEP(pW0, pW1, wq2.x, wq2.y, wq2.z, wq2.w);
        CSTEP(pW0, pW1, wq3.x, wq3.y, wq3.z, wq3.w);
    }
    __syncthreads();                                     // barrier #1

    // ---- main tile row -> registers; pass 1 (A^16 per thread) ----
    float xv[LPT];
#pragma unroll
    for (int t = 0; t < LPT; ++t) xv[t] = lds[tid][t];

    float pB0 = 0.f, pB1 = 0.f;
#pragma unroll
    for (int i = 0; i < LPT / 4; ++i)
        CSTEP(pB0, pB1, xv[4 * i], xv[4 * i + 1], xv[4 * i + 2], xv[4 * i + 3]);

    // ---- chunk matrix M = A^16 (2 squarings from A^4) ----
    float m00 = q00, m01 = q01, m10 = q10, m11 = q11;
    MATSQ(m00, m01, m10, m11);                           // A^8
    MATSQ(m00, m01, m10, m11);                           // A^16

    // ---- dual in-wave inclusive scan, ONE shared matrix track ----
    float wm00 = m00, wm01 = m01, wm10 = m10, wm11 = m11;
    for (int d = 1; d < 64; d <<= 1) {
        float oW0 = __shfl_up(pW0, d), oW1 = __shfl_up(pW1, d);
        float oB0 = __shfl_up(pB0, d), oB1 = __shfl_up(pB1, d);
        if (lane >= d) {
            pW0 = fmaf(wm00, oW0, fmaf(wm01, oW1, pW0));
            pW1 = fmaf(wm10, oW0, fmaf(wm11, oW1, pW1));
            pB0 = fmaf(wm00, oB0, fmaf(wm01, oB1, pB0));
            pB1 = fmaf(wm10, oB0, fmaf(wm11, oB1, pB1));
        }
        MATSQ(wm00, wm01, wm10, wm11);
    }
    // post-scan: wm = M^64 = A^1024 = Q

    // in-wave exclusive prefix for the main tile
    float ein0 = __shfl_up(pB0, 1), ein1 = __shfl_up(pB1, 1);
    if (lane == 0) { ein0 = 0.f; ein1 = 0.f; }

    if (lane == 63) {
        swv[4 * w]     = pW0; swv[4 * w + 1] = pW1;
        swv[4 * w + 2] = pB0; swv[4 * w + 3] = pB1;
    }
    __syncthreads();                                     // barrier #2

    // ---- Horner over wave aggregates with Q = A^1024 ----
    // sA = warm-up total = tile-start state (spans 4096 = 4 x 1024)
    float sA0 = 0.f, sA1 = 0.f;
#pragma unroll
    for (int u = 0; u < 4; ++u) {
        float t0 = fmaf(wm00, sA0, fmaf(wm01, sA1, swv[4 * u]));
        float t1 = fmaf(wm10, sA0, fmaf(wm11, sA1, swv[4 * u + 1]));
        sA0 = t0; sA1 = t1;
    }
    // cross-wave exclusive prefix for the main tile
    float cw0 = 0.f, cw1 = 0.f;
    for (int u = 0; u < w; ++u) {                         // <=3 iters
        float t0 = fmaf(wm00, cw0, fmaf(wm01, cw1, swv[4 * u + 2]));
        float t1 = fmaf(wm10, cw0, fmaf(wm11, cw1, swv[4 * u + 3]));
        cw0 = t0; cw1 = t1;
    }

    // ---- shared ladder (M = A^16): v = M^tid*sA + M^lane*cw + ein ----
    float vs0 = sA0, vs1 = sA1;
    float vc0 = cw0, vc1 = cw1;
    {
        float t00 = m00, t01 = m01, t10 = m10, t11 = m11;
#pragma unroll
        for (int bit = 0; bit < 8; ++bit) {
            if ((tid >> bit) & 1) {
                float n0 = fmaf(t00, vs0, t01 * vs1);
                float n1 = fmaf(t10, vs0, t11 * vs1);
                vs0 = n0; vs1 = n1;
                if (bit < 6) {                   // lane bits == tid bits 0..5
                    float u0 = fmaf(t00, vc0, t01 * vc1);
                    float u1 = fmaf(t10, vc0, t11 * vc1);
                    vc0 = u0; vc1 = u1;
                }
            }
            MATSQ(t00, t01, t10, t11);
        }
    }
    float v0 = vs0 + vc0 + ein0;
    float v1 = vs1 + vc1 + ein1;

    // ---- pass 2: Direct-Form-I from register x, outputs into LDS ----
    float o2 = fmaf(xv[0], b0, v0);                       // out_0
    float vn0 = fmaf(na1, o2, fmaf(xv[0], b1, v1));       // v0 at t=1
    float o1 = fmaf(xv[1], b0, vn0);                      // out_1
    lds[tid][0] = o2; lds[tid][1] = o1;
#pragma unroll
    for (int t = 2; t < LPT; ++t) {
        float acc = fmaf(b1, xv[t - 1], fmaf(b2, xv[t - 2], na2 * o2));
        float o   = fmaf(b0, xv[t], fmaf(na1, o1, acc));
        lds[tid][t] = o;
        o2 = o1; o1 = o;
    }
    __syncthreads();                                     // barrier #3

    // ---- coalesced NON-TEMPORAL store ----
    vfloat4* dst = reinterpret_cast<vfloat4*>(out + base);
#pragma unroll
    for (int it = 0; it < TILE / (TPB * 4); ++it) {
        int idx = it * TPB + tid;
        int e = idx * 4, c = e >> 4, t = e & 15;
        vfloat4 v;
        v.x = lds[c][t];     v.y = lds[c][t + 1];
        v.z = lds[c][t + 2]; v.w = lds[c][t + 3];
        __builtin_nontemporal_store(v, &dst[idx]);
    }
}

extern "C" void kernel_launch(void* const* d_in, const int* in_sizes, int n_in,
                              void* d_out, int out_size, void* d_ws, size_t ws_size,
                              hipStream_t stream) {
    const float* x   = (const float*)d_in[0];
    const float* pb0 = (const float*)d_in[1];
    const float* pb1 = (const float*)d_in[2];
    const float* pb2 = (const float*)d_in[3];
    const float* pa1 = (const float*)d_in[4];
    const float* pa2 = (const float*)d_in[5];
    float* out = (float*)d_out;

    biquad_hires<<<NB, TPB, 0, stream>>>(x, out, pb0, pb1, pb2, pa1, pa2);
}

// Round 14
// 26.749 us; speedup vs baseline: 1.5782x; 1.5782x over previous
//
#include <hip/hip_runtime.h>

// Direct-Form-II biquad over [B=64][T=262144], FULLY INDEPENDENT blocks via
// warm-up truncation (round-11 winner) + XCD-aware chunked blockIdx swizzle:
// chain-consecutive blocks land on the SAME XCD so block g's warm-up region
// (= block g-1's tile) is a local-L2 hit instead of a cross-die L3/HBM read.
//   v[t+1] = A v[t] + c x[t],  A = [[-a1,1],[-a2,0]],  c = [b1-a1*b0, b2-a2*b0]
//   out[t] = b0 x[t] + v0[t]
// Tile = 8192 samples; tile-start state from 4096 preceding samples, zero-init
// (stable filter; truncation err ~ rho^4096, verified by absmax). No atomics,
// no workspace, 3 barriers.

constexpr int BATCH = 64;
constexpr int T_LEN = 262144;
constexpr int TPB   = 256;            // threads per block
constexpr int LPT   = 32;             // samples per thread (main tile)
constexpr int TILE  = TPB * LPT;      // 8192 samples per block
constexpr int NBPB  = T_LEN / TILE;   // 32 blocks per batch chain
constexpr int NB    = BATCH * NBPB;   // 2048 blocks
constexpr int WUP   = 4096;           // warm-up samples
constexpr int NXCD  = 8;
constexpr int CPX   = NB / NXCD;      // 256 work-ids per XCD chunk

typedef float vfloat4 __attribute__((ext_vector_type(4)));

#define MATSQ(m00, m01, m10, m11)                                  \
    {                                                              \
        float n00 = fmaf(m00, m00, m01 * m10);                     \
        float n01 = fmaf(m00, m01, m01 * m11);                     \
        float n10 = fmaf(m10, m00, m11 * m10);                     \
        float n11 = fmaf(m10, m01, m11 * m11);                     \
        m00 = n00; m01 = n01; m10 = n10; m11 = n11;                \
    }

// composed 4-step update: v <- A^4 v + k3*xa + k2*xb + k1*xc + c*xd
#define CSTEP(p0, p1, xa, xb, xc, xd)                                        \
    {                                                                        \
        float n0 = fmaf(q00, p0, fmaf(q01, p1,                               \
                   fmaf(k3_0, (xa), fmaf(k2_0, (xb),                         \
                   fmaf(k1_0, (xc), c0 * (xd))))));                          \
        float n1 = fmaf(q10, p0, fmaf(q11, p1,                               \
                   fmaf(k3_1, (xa), fmaf(k2_1, (xb),                         \
                   fmaf(k1_1, (xc), c1 * (xd))))));                          \
        p0 = n0; p1 = n1;                                                    \
    }

__global__ __launch_bounds__(TPB, 4) void biquad_trunc(
    const float* __restrict__ x, float* __restrict__ out,
    const float* __restrict__ pb0, const float* __restrict__ pb1,
    const float* __restrict__ pb2, const float* __restrict__ pa1,
    const float* __restrict__ pa2)
{
    __shared__ float lds[TPB][LPT + 1];   // padded tile: 33,792 B
    __shared__ float swv[16];             // wave aggregates: A pairs [0..7], B pairs [8..15]

    const int tid  = threadIdx.x;
    const int lane = tid & 63;
    const int w    = tid >> 6;            // wave index 0..3

    // XCD-aware chunked swizzle: dispatcher round-robins blockIdx across the
    // 8 XCDs, so (blockIdx & 7) == physical XCD. Give each XCD a CONTIGUOUS
    // range of work-ids -> chain neighbors share an L2. Bijective (NB%8==0).
    const int g    = (blockIdx.x & (NXCD - 1)) * CPX + (blockIdx.x >> 3);
    const int b    = g >> 5;              // batch
    const int k    = g & (NBPB - 1);      // chain position

    const float b0 = *pb0, b1 = *pb1, b2 = *pb2;
    const float a1 = *pa1, a2 = *pa2;
    const float na1 = -a1, na2 = -a2;

    // ---- composed constants ----
    // c = [b1-a1*b0, b2-a2*b0];  k1=Ac, k2=A^2 c, k3=A^3 c;  q=A^4
    const float c0 = fmaf(na1, b0, b1), c1 = fmaf(na2, b0, b2);
    const float A00 = na1, A01 = 1.f, A10 = na2, A11 = 0.f;
    const float k1_0 = fmaf(A00, c0, A01 * c1);
    const float k1_1 = fmaf(A10, c0, A11 * c1);
    float B00 = A00, B01 = A01, B10 = A10, B11 = A11;
    MATSQ(B00, B01, B10, B11);                           // A^2
    const float k2_0 = fmaf(B00, c0, B01 * c1);
    const float k2_1 = fmaf(B10, c0, B11 * c1);
    const float k3_0 = fmaf(B00, k1_0, B01 * k1_1);
    const float k3_1 = fmaf(B10, k1_0, B11 * k1_1);
    float q00 = B00, q01 = B01, q10 = B10, q11 = B11;
    MATSQ(q00, q01, q10, q11);                           // A^4

    const size_t base = (size_t)b * T_LEN + (size_t)k * TILE;

    // ---- warm-up: strided register loads of the 4096 preceding samples ----
    float4 wq[4];
    if (k > 0) {
        const float4* wsrc =
            reinterpret_cast<const float4*>(x + base - WUP) + tid * 4;
#pragma unroll
        for (int i = 0; i < 4; ++i) wq[i] = wsrc[i];
    }

    // ---- stage main tile: 8 coalesced float4 loads -> LDS (transpose) ----
    const float4* src = reinterpret_cast<const float4*>(x + base);
#pragma unroll
    for (int it = 0; it < 8; ++it) {
        int idx = it * TPB + tid;
        float4 v = src[idx];
        int e = idx * 4, c = e >> 5, t = e & 31;
        lds[c][t] = v.x; lds[c][t + 1] = v.y;
        lds[c][t + 2] = v.z; lds[c][t + 3] = v.w;
    }

    // ---- warm-up pass 1: per-thread A^16 particular state ----
    float pA0 = 0.f, pA1 = 0.f;
    if (k > 0) {
#pragma unroll
        for (int i = 0; i < 4; ++i)
            CSTEP(pA0, pA1, wq[i].x, wq[i].y, wq[i].z, wq[i].w);
    }
    __syncthreads();                                     // barrier #1

    // ---- main tile row -> registers; pass 1 (A^32 per thread) ----
    float xv[LPT];
#pragma unroll
    for (int t = 0; t < LPT; ++t) xv[t] = lds[tid][t];

    float pB0 = 0.f, pB1 = 0.f;
#pragma unroll
    for (int i = 0; i < LPT / 4; ++i)
        CSTEP(pB0, pB1, xv[4 * i], xv[4 * i + 1], xv[4 * i + 2], xv[4 * i + 3]);

    // ---- chunk matrices: MA = A^16 (2 sq from A^4), MB = A^32 (1 more) ----
    float wa00 = q00, wa01 = q01, wa10 = q10, wa11 = q11;
    MATSQ(wa00, wa01, wa10, wa11);                       // A^8
    MATSQ(wa00, wa01, wa10, wa11);                       // A^16
    float m00 = wa00, m01 = wa01, m10 = wa10, m11 = wa11;
    MATSQ(m00, m01, m10, m11);                           // A^32
    float wb00 = m00, wb01 = m01, wb10 = m10, wb11 = m11;

    // ---- dual in-wave inclusive scan (shfl only) ----
    for (int d = 1; d < 64; d <<= 1) {
        float oA0 = __shfl_up(pA0, d), oA1 = __shfl_up(pA1, d);
        float oB0 = __shfl_up(pB0, d), oB1 = __shfl_up(pB1, d);
        if (lane >= d) {
            pA0 = fmaf(wa00, oA0, fmaf(wa01, oA1, pA0));
            pA1 = fmaf(wa10, oA0, fmaf(wa11, oA1, pA1));
            pB0 = fmaf(wb00, oB0, fmaf(wb01, oB1, pB0));
            pB1 = fmaf(wb10, oB0, fmaf(wb11, oB1, pB1));
        }
        MATSQ(wa00, wa01, wa10, wa11);
        MATSQ(wb00, wb01, wb10, wb11);
    }
    // after the loop: wa = A^1024 (QA), wb = A^2048 (QB)

    // in-wave exclusive prefix for B
    float einB0 = __shfl_up(pB0, 1);
    float einB1 = __shfl_up(pB1, 1);
    if (lane == 0) { einB0 = 0.f; einB1 = 0.f; }

    if (lane == 63) {
        swv[2 * w] = pA0;     swv[2 * w + 1] = pA1;
        swv[8 + 2 * w] = pB0; swv[9 + 2 * w] = pB1;
    }
    __syncthreads();                                     // barrier #2

    // ---- sA = warm-up total aggregate (tile-start state), Horner with QA ----
    float sA0 = 0.f, sA1 = 0.f;
#pragma unroll
    for (int u = 0; u < 4; ++u) {
        float t0 = fmaf(wa00, sA0, fmaf(wa01, sA1, swv[2 * u]));
        float t1 = fmaf(wa10, sA0, fmaf(wa11, sA1, swv[2 * u + 1]));
        sA0 = t0; sA1 = t1;
    }
    // ---- cross-wave exclusive prefix for B, Horner with QB ----
    float cw0 = 0.f, cw1 = 0.f;
    for (int u = 0; u < w; ++u) {                         // <=3 iters
        float t0 = fmaf(wb00, cw0, fmaf(wb01, cw1, swv[8 + 2 * u]));
        float t1 = fmaf(wb10, cw0, fmaf(wb11, cw1, swv[9 + 2 * u]));
        cw0 = t0; cw1 = t1;
    }

    // ---- shared ladder: vs = M^tid * sA,  vc = M^lane * cw   (M = A^32) ----
    float vs0 = sA0, vs1 = sA1;
    float vc0 = cw0, vc1 = cw1;
    {
        float t00 = m00, t01 = m01, t10 = m10, t11 = m11;
#pragma unroll
        for (int bit = 0; bit < 8; ++bit) {
            if ((tid >> bit) & 1) {
                float n0 = fmaf(t00, vs0, t01 * vs1);
                float n1 = fmaf(t10, vs0, t11 * vs1);
                vs0 = n0; vs1 = n1;
                if (bit < 6) {                   // lane bits == tid bits 0..5
                    float u0 = fmaf(t00, vc0, t01 * vc1);
                    float u1 = fmaf(t10, vc0, t11 * vc1);
                    vc0 = u0; vc1 = u1;
                }
            }
            MATSQ(t00, t01, t10, t11);
        }
    }
    float v0 = vs0 + vc0 + einB0;
    float v1 = vs1 + vc1 + einB1;

    // ---- pass 2: Direct-Form-I from register x, outputs into LDS ----
    float o2 = fmaf(xv[0], b0, v0);                       // out_0
    float vn0 = fmaf(na1, o2, fmaf(xv[0], b1, v1));       // v0 at t=1
    float o1 = fmaf(xv[1], b0, vn0);                      // out_1
    lds[tid][0] = o2; lds[tid][1] = o1;
#pragma unroll
    for (int t = 2; t < LPT; ++t) {
        float acc = fmaf(b1, xv[t - 1], fmaf(b2, xv[t - 2], na2 * o2));
        float o   = fmaf(b0, xv[t], fmaf(na1, o1, acc));
        lds[tid][t] = o;
        o2 = o1; o1 = o;
    }
    __syncthreads();                                     // barrier #3

    // ---- coalesced NON-TEMPORAL store ----
    vfloat4* dst = reinterpret_cast<vfloat4*>(out + base);
#pragma unroll
    for (int it = 0; it < 8; ++it) {
        int idx = it * TPB + tid;
        int e = idx * 4, c = e >> 5, t = e & 31;
        vfloat4 v;
        v.x = lds[c][t];     v.y = lds[c][t + 1];
        v.z = lds[c][t + 2]; v.w = lds[c][t + 3];
        __builtin_nontemporal_store(v, &dst[idx]);
    }
}

extern "C" void kernel_launch(void* const* d_in, const int* in_sizes, int n_in,
                              void* d_out, int out_size, void* d_ws, size_t ws_size,
                              hipStream_t stream) {
    const float* x   = (const float*)d_in[0];
    const float* pb0 = (const float*)d_in[1];
    const float* pb1 = (const float*)d_in[2];
    const float* pb2 = (const float*)d_in[3];
    const float* pa1 = (const float*)d_in[4];
    const float* pa2 = (const float*)d_in[5];
    float* out = (float*)d_out;

    biquad_trunc<<<NB, TPB, 0, stream>>>(x, out, pb0, pb1, pb2, pa1, pa2);
}

// Round 15
// 26.693 us; speedup vs baseline: 1.5815x; 1.0021x over previous
//
#include <hip/hip_runtime.h>

// Direct-Form-II biquad over [B=64][T=262144], fully independent blocks
// (warm-up truncation) + XCD-aware chunked swizzle (r14 winner), now with
// DIRECT per-thread global loads (no input LDS staging, no barrier #1):
// thread tid reads its 32 contiguous samples straight from global (8 x
// float4, 128-B lane stride -- same pattern the warm-up loads already use).
// LDS is used only to transpose outputs for coalesced NT stores.
//   v[t+1] = A v[t] + c x[t],  A = [[-a1,1],[-a2,0]],  c = [b1-a1*b0, b2-a2*b0]
//   out[t] = b0 x[t] + v0[t]

constexpr int BATCH = 64;
constexpr int T_LEN = 262144;
constexpr int TPB   = 256;            // threads per block
constexpr int LPT   = 32;             // samples per thread (main tile)
constexpr int TILE  = TPB * LPT;      // 8192 samples per block
constexpr int NBPB  = T_LEN / TILE;   // 32 blocks per batch chain
constexpr int NB    = BATCH * NBPB;   // 2048 blocks
constexpr int WUP   = 4096;           // warm-up samples
constexpr int NXCD  = 8;
constexpr int CPX   = NB / NXCD;      // 256 work-ids per XCD chunk

typedef float vfloat4 __attribute__((ext_vector_type(4)));

#define MATSQ(m00, m01, m10, m11)                                  \
    {                                                              \
        float n00 = fmaf(m00, m00, m01 * m10);                     \
        float n01 = fmaf(m00, m01, m01 * m11);                     \
        float n10 = fmaf(m10, m00, m11 * m10);                     \
        float n11 = fmaf(m10, m01, m11 * m11);                     \
        m00 = n00; m01 = n01; m10 = n10; m11 = n11;                \
    }

// composed 4-step update: v <- A^4 v + k3*xa + k2*xb + k1*xc + c*xd
#define CSTEP(p0, p1, xa, xb, xc, xd)                                        \
    {                                                                        \
        float n0 = fmaf(q00, p0, fmaf(q01, p1,                               \
                   fmaf(k3_0, (xa), fmaf(k2_0, (xb),                         \
                   fmaf(k1_0, (xc), c0 * (xd))))));                          \
        float n1 = fmaf(q10, p0, fmaf(q11, p1,                               \
                   fmaf(k3_1, (xa), fmaf(k2_1, (xb),                         \
                   fmaf(k1_1, (xc), c1 * (xd))))));                          \
        p0 = n0; p1 = n1;                                                    \
    }

__global__ __launch_bounds__(TPB, 4) void biquad_direct(
    const float* __restrict__ x, float* __restrict__ out,
    const float* __restrict__ pb0, const float* __restrict__ pb1,
    const float* __restrict__ pb2, const float* __restrict__ pa1,
    const float* __restrict__ pa2)
{
    __shared__ float lds[TPB][LPT + 1];   // output transpose buffer: 33,792 B
    __shared__ float swv[16];             // wave aggregates: W pairs [0..7], B pairs [8..15]

    const int tid  = threadIdx.x;
    const int lane = tid & 63;
    const int w    = tid >> 6;            // wave index 0..3

    // XCD-aware chunked swizzle (bijective: NB % 8 == 0)
    const int g    = (blockIdx.x & (NXCD - 1)) * CPX + (blockIdx.x >> 3);
    const int b    = g >> 5;              // batch
    const int k    = g & (NBPB - 1);      // chain position

    const float b0 = *pb0, b1 = *pb1, b2 = *pb2;
    const float a1 = *pa1, a2 = *pa2;
    const float na1 = -a1, na2 = -a2;

    // ---- composed constants ----
    const float c0 = fmaf(na1, b0, b1), c1 = fmaf(na2, b0, b2);
    const float A00 = na1, A01 = 1.f, A10 = na2, A11 = 0.f;
    const float k1_0 = fmaf(A00, c0, A01 * c1);
    const float k1_1 = fmaf(A10, c0, A11 * c1);
    float B00 = A00, B01 = A01, B10 = A10, B11 = A11;
    MATSQ(B00, B01, B10, B11);                           // A^2
    const float k2_0 = fmaf(B00, c0, B01 * c1);
    const float k2_1 = fmaf(B10, c0, B11 * c1);
    const float k3_0 = fmaf(B00, k1_0, B01 * k1_1);
    const float k3_1 = fmaf(B10, k1_0, B11 * k1_1);
    float q00 = B00, q01 = B01, q10 = B10, q11 = B11;
    MATSQ(q00, q01, q10, q11);                           // A^4

    const size_t base = (size_t)b * T_LEN + (size_t)k * TILE;

    // ---- issue ALL global loads up front (no LDS staging) ----
    // main tile: thread's 32 contiguous samples = 8 x float4 (128-B lane stride)
    const float4* xrow = reinterpret_cast<const float4*>(x + base) + tid * (LPT / 4);
    float4 xq[8];
#pragma unroll
    for (int i = 0; i < 8; ++i) xq[i] = xrow[i];

    // warm-up: 16 preceding-region samples per thread (64-B lane stride)
    float4 wq[4];
    if (k > 0) {
        const float4* wsrc =
            reinterpret_cast<const float4*>(x + base - WUP) + tid * 4;
#pragma unroll
        for (int i = 0; i < 4; ++i) wq[i] = wsrc[i];
    }

    // ---- pass 1: warm-up carry (A^16) and main-tile carry (A^32) ----
    float pA0 = 0.f, pA1 = 0.f;
    if (k > 0) {
#pragma unroll
        for (int i = 0; i < 4; ++i)
            CSTEP(pA0, pA1, wq[i].x, wq[i].y, wq[i].z, wq[i].w);
    }
    float pB0 = 0.f, pB1 = 0.f;
#pragma unroll
    for (int i = 0; i < 8; ++i)
        CSTEP(pB0, pB1, xq[i].x, xq[i].y, xq[i].z, xq[i].w);

    // ---- chunk matrices: MA = A^16, MB = A^32 ----
    float wa00 = q00, wa01 = q01, wa10 = q10, wa11 = q11;
    MATSQ(wa00, wa01, wa10, wa11);                       // A^8
    MATSQ(wa00, wa01, wa10, wa11);                       // A^16
    float m00 = wa00, m01 = wa01, m10 = wa10, m11 = wa11;
    MATSQ(m00, m01, m10, m11);                           // A^32
    float wb00 = m00, wb01 = m01, wb10 = m10, wb11 = m11;

    // ---- dual in-wave inclusive scan (shfl only) ----
    for (int d = 1; d < 64; d <<= 1) {
        float oA0 = __shfl_up(pA0, d), oA1 = __shfl_up(pA1, d);
        float oB0 = __shfl_up(pB0, d), oB1 = __shfl_up(pB1, d);
        if (lane >= d) {
            pA0 = fmaf(wa00, oA0, fmaf(wa01, oA1, pA0));
            pA1 = fmaf(wa10, oA0, fmaf(wa11, oA1, pA1));
            pB0 = fmaf(wb00, oB0, fmaf(wb01, oB1, pB0));
            pB1 = fmaf(wb10, oB0, fmaf(wb11, oB1, pB1));
        }
        MATSQ(wa00, wa01, wa10, wa11);
        MATSQ(wb00, wb01, wb10, wb11);
    }
    // post-scan: wa = A^1024 (QA), wb = A^2048 (QB)

    // in-wave exclusive prefix for B
    float einB0 = __shfl_up(pB0, 1);
    float einB1 = __shfl_up(pB1, 1);
    if (lane == 0) { einB0 = 0.f; einB1 = 0.f; }

    if (lane == 63) {
        swv[2 * w] = pA0;     swv[2 * w + 1] = pA1;
        swv[8 + 2 * w] = pB0; swv[9 + 2 * w] = pB1;
    }
    __syncthreads();                                     // barrier #1

    // ---- sA = warm-up total (tile-start state), Horner with QA ----
    float sA0 = 0.f, sA1 = 0.f;
#pragma unroll
    for (int u = 0; u < 4; ++u) {
        float t0 = fmaf(wa00, sA0, fmaf(wa01, sA1, swv[2 * u]));
        float t1 = fmaf(wa10, sA0, fmaf(wa11, sA1, swv[2 * u + 1]));
        sA0 = t0; sA1 = t1;
    }
    // ---- cross-wave exclusive prefix for B, Horner with QB ----
    float cw0 = 0.f, cw1 = 0.f;
    for (int u = 0; u < w; ++u) {                         // <=3 iters
        float t0 = fmaf(wb00, cw0, fmaf(wb01, cw1, swv[8 + 2 * u]));
        float t1 = fmaf(wb10, cw0, fmaf(wb11, cw1, swv[9 + 2 * u]));
        cw0 = t0; cw1 = t1;
    }

    // ---- shared ladder: vs = M^tid * sA,  vc = M^lane * cw   (M = A^32) ----
    float vs0 = sA0, vs1 = sA1;
    float vc0 = cw0, vc1 = cw1;
    {
        float t00 = m00, t01 = m01, t10 = m10, t11 = m11;
#pragma unroll
        for (int bit = 0; bit < 8; ++bit) {
            if ((tid >> bit) & 1) {
                float n0 = fmaf(t00, vs0, t01 * vs1);
                float n1 = fmaf(t10, vs0, t11 * vs1);
                vs0 = n0; vs1 = n1;
                if (bit < 6) {                   // lane bits == tid bits 0..5
                    float u0 = fmaf(t00, vc0, t01 * vc1);
                    float u1 = fmaf(t10, vc0, t11 * vc1);
                    vc0 = u0; vc1 = u1;
                }
            }
            MATSQ(t00, t01, t10, t11);
        }
    }
    float v0 = vs0 + vc0 + einB0;
    float v1 = vs1 + vc1 + einB1;

    // ---- pass 2: Direct-Form-I from registers, outputs into LDS rows ----
    {
        float xm2 = xq[0].x, xm1 = xq[0].y;
        float o2 = fmaf(xm2, b0, v0);                     // out_0
        float vn0 = fmaf(na1, o2, fmaf(xm2, b1, v1));     // v0 at t=1
        float o1 = fmaf(xm1, b0, vn0);                    // out_1
        lds[tid][0] = o2; lds[tid][1] = o1;
#pragma unroll
        for (int t = 2; t < LPT; ++t) {
            float xt = (t & 3) == 0 ? xq[t >> 2].x :
                       (t & 3) == 1 ? xq[t >> 2].y :
                       (t & 3) == 2 ? xq[t >> 2].z : xq[t >> 2].w;
            float acc = fmaf(b1, xm1, fmaf(b2, xm2, na2 * o2));
            float o   = fmaf(b0, xt, fmaf(na1, o1, acc));
            lds[tid][t] = o;
            xm2 = xm1; xm1 = xt;
            o2 = o1; o1 = o;
        }
    }
    __syncthreads();                                     // barrier #2

    // ---- coalesced NON-TEMPORAL store ----
    vfloat4* dst = reinterpret_cast<vfloat4*>(out + base);
#pragma unroll
    for (int it = 0; it < 8; ++it) {
        int idx = it * TPB + tid;
        int e = idx * 4, c = e >> 5, t = e & 31;
        vfloat4 v;
        v.x = lds[c][t];     v.y = lds[c][t + 1];
        v.z = lds[c][t + 2]; v.w = lds[c][t + 3];
        __builtin_nontemporal_store(v, &dst[idx]);
    }
}

extern "C" void kernel_launch(void* const* d_in, const int* in_sizes, int n_in,
                              void* d_out, int out_size, void* d_ws, size_t ws_size,
                              hipStream_t stream) {
    const float* x   = (const float*)d_in[0];
    const float* pb0 = (const float*)d_in[1];
    const float* pb1 = (const float*)d_in[2];
    const float* pb2 = (const float*)d_in[3];
    const float* pa1 = (const float*)d_in[4];
    const float* pa2 = (const float*)d_in[5];
    float* out = (float*)d_out;

    biquad_direct<<<NB, TPB, 0, stream>>>(x, out, pb0, pb1, pb2, pa1, pa2);
}